// Round 1
// baseline (409.318 us; speedup 1.0000x reference)
//
#include <hip/hip_runtime.h>
#include <hip/hip_bf16.h>
#include <stdint.h>

#define N_NODES 50000
#define N_EDGES 500000
#define R_REL 8
#define HID 128
#define KIN 128              // input features per slab
#define KOUT 1152            // 9*128: concat K dim (W_0..W_7 | root)
#define N8 400000            // N_NODES * R_REL composite buckets
#define NUM_GRAPHS 64
#define NUM_CLASSES 16

#define BN 32                // dst-nodes per fused block
#define LDA 1160             // A row stride in shorts (1152 + 8 pad -> 2320 B, 145*16B, conflict-free)
#define NKC 36               // K chunks of 32 (1152/32)
#define NBLK 1563            // ceil(50000/32)

typedef __attribute__((ext_vector_type(8))) short bf16x8;
typedef __attribute__((ext_vector_type(4))) float f32x4;

// ---------- helpers ----------
__device__ __forceinline__ uint16_t f2bf(float f) {
  uint32_t u = __float_as_uint(f);
  u += 0x7FFFu + ((u >> 16) & 1u);   // RNE
  return (uint16_t)(u >> 16);
}
__device__ __forceinline__ float bf2f(uint32_t b) {
  return __uint_as_float(b << 16);
}
__device__ __forceinline__ uint32_t pack2bf(float a, float b) {
  return (uint32_t)f2bf(a) | ((uint32_t)f2bf(b) << 16);
}

// ---------- merged prep: hist | bounds | prepw1 | prepw2 | x->bf16 ----------
#define HIST_B 1954
#define BND_B 196
#define PW_B 576            // KOUT*KIN / 256
#define CVT_B 3125          // N_NODES*HID/8 / 256
__global__ __launch_bounds__(256) void k_prep(const int* __restrict__ ei, const int* __restrict__ et,
                                              int* __restrict__ deg8,
                                              const int* __restrict__ batch,
                                              int* __restrict__ gs, int* __restrict__ ge,
                                              const float* __restrict__ W1, const float* __restrict__ root1,
                                              uint16_t* __restrict__ Wf1,
                                              const float* __restrict__ W2, const float* __restrict__ root2,
                                              uint16_t* __restrict__ Wf2,
                                              const float* __restrict__ x, uint16_t* __restrict__ xb) {
  int b = blockIdx.x;
  if (b < HIST_B) {                                 // edge histogram
    int i = b * 256 + threadIdx.x;
    if (i < N_EDGES) atomicAdd(&deg8[ei[N_EDGES + i] * R_REL + et[i]], 1);
    return;
  }
  b -= HIST_B;
  if (b < BND_B) {                                  // graph boundaries (batch sorted)
    int i = b * 256 + threadIdx.x;
    if (i < N_NODES) {
      int g = batch[i];
      if (i == 0) gs[g] = 0;
      else { int pg = batch[i - 1]; if (pg != g) { ge[pg] = i; gs[g] = i; } }
      if (i == N_NODES - 1) ge[g] = N_NODES;
    }
    return;
  }
  b -= BND_B;
  if (b < 2 * PW_B) {
    // prepw: Wf in B-frag order for K=1152 GEMM. frag f = kc*8 + nt (kc 0..35, nt 0..7).
    // lane L=(quad,l16), elem e: B[kk = kc*32+quad*8+e][col = nt*16+l16], kk -> slab s=kk>>7, k=kk&127
    const float* W    = (b < PW_B) ? W1 : W2;
    const float* root = (b < PW_B) ? root1 : root2;
    uint16_t*    Wf   = (b < PW_B) ? Wf1 : Wf2;
    int idx = (b % PW_B) * 256 + threadIdx.x;       // over KOUT*KIN
    int e = idx & 7, L = (idx >> 3) & 63, f = idx >> 9;
    int quad = L >> 4, l16 = L & 15;
    int nt = f & 7, kc = f >> 3;
    int kk = kc * 32 + quad * 8 + e;
    int s = kk >> 7, k = kk & 127;
    int col = nt * 16 + l16;
    float v = (s < R_REL) ? W[((size_t)s * KIN + k) * HID + col] : root[(size_t)k * HID + col];
    Wf[idx] = f2bf(v);
    return;
  }
  b -= 2 * PW_B;
  {                                                 // x (fp32) -> xb (bf16), 8 elems/thread
    int i = b * 256 + threadIdx.x;                  // < 800000 exact
    const float4* p = (const float4*)x + (size_t)i * 2;
    float4 a = p[0], c = p[1];
    uint4 o;
    o.x = pack2bf(a.x, a.y); o.y = pack2bf(a.z, a.w);
    o.z = pack2bf(c.x, c.y); o.w = pack2bf(c.z, c.w);
    *(uint4*)(xb + (size_t)i * 8) = o;
  }
}

// ---------- scans ----------
__global__ __launch_bounds__(256) void k_scan1(const int* __restrict__ deg8, int* __restrict__ offs8,
                                               int* __restrict__ bsum) {
  __shared__ int sh[256];
  int t = threadIdx.x;
  int base = blockIdx.x * 1024 + t * 4;
  int v[4]; int s = 0;
  #pragma unroll
  for (int i = 0; i < 4; ++i) { int idx = base + i; v[i] = (idx < N8) ? deg8[idx] : 0; s += v[i]; }
  sh[t] = s;
  __syncthreads();
  for (int d = 1; d < 256; d <<= 1) {
    int add = (t >= d) ? sh[t - d] : 0;
    __syncthreads();
    sh[t] += add;
    __syncthreads();
  }
  int run = sh[t] - s;
  if (t == 255) bsum[blockIdx.x] = sh[255];
  #pragma unroll
  for (int i = 0; i < 4; ++i) { int idx = base + i; if (idx < N8) offs8[idx] = run; run += v[i]; }
}

__global__ __launch_bounds__(512) void k_scan2(int* __restrict__ bsum, int nb) {
  __shared__ int sh[512];
  int t = threadIdx.x;
  int v = (t < nb) ? bsum[t] : 0;
  sh[t] = v;
  __syncthreads();
  for (int d = 1; d < 512; d <<= 1) {
    int add = (t >= d) ? sh[t - d] : 0;
    __syncthreads();
    sh[t] += add;
    __syncthreads();
  }
  if (t < nb) bsum[t] = sh[t] - v;   // exclusive
}

__global__ __launch_bounds__(256) void k_scan3(int* __restrict__ offs8, int* __restrict__ nxt,
                                               const int* __restrict__ bsum) {
  int i = blockIdx.x * 256 + threadIdx.x;
  if (i < N8) {
    int o = offs8[i] + bsum[i >> 10];
    offs8[i] = o;
    nxt[i] = o;
  }
  if (i == 0) offs8[N8] = N_EDGES;
}

// scatter: place edge; also emit per-edge packed (src|rel<<16) and weight 1/cnt
__global__ __launch_bounds__(256) void k_scatter(const int* __restrict__ ei, const int* __restrict__ et,
                                                 const int* __restrict__ deg8, int* __restrict__ nxt,
                                                 uint32_t* __restrict__ epack, float* __restrict__ wgt) {
  int i = blockIdx.x * 256 + threadIdx.x;
  if (i < N_EDGES) {
    int rel = et[i];
    int key = ei[N_EDGES + i] * R_REL + rel;
    int p = atomicAdd(&nxt[key], 1);
    epack[p] = (uint32_t)ei[i] | ((uint32_t)rel << 16);   // src < 2^16
    wgt[p] = 1.0f / (float)deg8[key];                     // mean weight (cnt >= 1)
  }
}

// ---------- fused layer: aggregate-then-transform ----------
// Block = 32 dst nodes, 256 threads (4 waves), LDS A[32][1160] bf16 (74240 B -> 2 blocks/CU).
// Phase 1: wave w aggregates nodes w*8..w*8+8: per node, pipelined gathers of h[src] (u32/lane),
//          per-(rel) fp32 accumulate, flush-on-rel-change into LDS slab; root slab = own h.
// Phase 2: GEMM out[32,128] = A[32,1152] @ Wcat[1152,128]; wave w owns cols [w*32, w*32+32).
template<bool OUT_BF16>
__global__ __launch_bounds__(256, 2) void k_fused(const uint16_t* __restrict__ hin,
                                                  const uint32_t* __restrict__ epack,
                                                  const float* __restrict__ wgt,
                                                  const int* __restrict__ offs8,
                                                  const uint16_t* __restrict__ Wf,
                                                  const float* __restrict__ bias,
                                                  void* __restrict__ hout) {
  __shared__ __align__(16) uint16_t As[BN * LDA];
  int t = threadIdx.x;
  int w = __builtin_amdgcn_readfirstlane(t >> 6);
  int L = t & 63;
  int quad = L >> 4, l16 = L & 15;
  int node0 = blockIdx.x * BN;

  // zero A tile: 32*1160 = 37120 shorts = 4640 b128 chunks
  {
    bf16x8 z = 0;
    #pragma unroll
    for (int i = 0; i < 18; ++i) ((bf16x8*)As)[i * 256 + t] = z;
    if (t < 32) ((bf16x8*)As)[18 * 256 + t] = z;
  }
  __syncthreads();

  // ---- phase 1: aggregation (wave per node, lane = 2 dims) ----
  #pragma unroll 1
  for (int ni = 0; ni < 8; ++ni) {
    int nl = w * 8 + ni;
    int n = node0 + nl;
    if (n >= N_NODES) break;
    uint16_t* Arow = As + nl * LDA;
    // root slab (s=8): direct bf16 copy of own features
    *(uint32_t*)(Arow + R_REL * HID + L * 2) =
        *(const uint32_t*)(hin + (size_t)n * HID + L * 2);
    int o0 = offs8[n * R_REL];
    int o8 = offs8[n * R_REL + R_REL];
    float ax = 0.f, ay = 0.f;
    int cur = -1;
    for (int g = o0; g < o8; g += 8) {
      int m8 = min(8, o8 - g);
      uint32_t pv[8]; float wv[8]; uint32_t vv[8];
      #pragma unroll
      for (int i = 0; i < 8; ++i) if (i < m8) { pv[i] = epack[g + i]; wv[i] = wgt[g + i]; }
      #pragma unroll
      for (int i = 0; i < 8; ++i) if (i < m8)
        vv[i] = *(const uint32_t*)(hin + (size_t)(pv[i] & 0xFFFFu) * HID + L * 2);
      #pragma unroll
      for (int i = 0; i < 8; ++i) if (i < m8) {
        int r = (int)(pv[i] >> 16);           // wave-uniform (same edge across lanes)
        if (r != cur) {                        // edges sorted by (dst,rel): flush finished slab
          if (cur >= 0) *(uint32_t*)(Arow + cur * HID + L * 2) = pack2bf(ax, ay);
          ax = 0.f; ay = 0.f; cur = r;
        }
        ax += bf2f(vv[i] & 0xFFFFu) * wv[i];
        ay += bf2f(vv[i] >> 16) * wv[i];
      }
    }
    if (cur >= 0) *(uint32_t*)(Arow + cur * HID + L * 2) = pack2bf(ax, ay);
  }
  __syncthreads();

  // ---- phase 2: GEMM. wave w: rows 0..32 (2 m-frags) x cols [w*32, w*32+32) (2 n-frags) ----
  f32x4 acc[2][2];
  #pragma unroll
  for (int m = 0; m < 2; ++m)
    #pragma unroll
    for (int j = 0; j < 2; ++j) acc[m][j] = (f32x4){0.f, 0.f, 0.f, 0.f};

  const uint16_t* wp = Wf + (size_t)(w * 2) * 512 + (size_t)L * 8;   // frag f=kc*8+(w*2+j), +4096/kc
  const uint16_t* ap = As + l16 * LDA + quad * 8;                    // A[m*16+l16][kc*32+quad*8+e]

  bf16x8 b0 = *(const bf16x8*)wp;
  bf16x8 b1 = *(const bf16x8*)(wp + 512);
  bf16x8 a0 = *(const bf16x8*)ap;
  bf16x8 a1 = *(const bf16x8*)(ap + 16 * LDA);

  #pragma unroll 1
  for (int kc = 0; kc < NKC - 1; ++kc) {
    const uint16_t* wpn = wp + (size_t)(kc + 1) * 4096;
    bf16x8 nb0 = *(const bf16x8*)wpn;
    bf16x8 nb1 = *(const bf16x8*)(wpn + 512);
    const uint16_t* apn = ap + (kc + 1) * 32;
    bf16x8 na0 = *(const bf16x8*)apn;
    bf16x8 na1 = *(const bf16x8*)(apn + 16 * LDA);
    acc[0][0] = __builtin_amdgcn_mfma_f32_16x16x32_bf16(a0, b0, acc[0][0], 0, 0, 0);
    acc[1][0] = __builtin_amdgcn_mfma_f32_16x16x32_bf16(a1, b0, acc[1][0], 0, 0, 0);
    acc[0][1] = __builtin_amdgcn_mfma_f32_16x16x32_bf16(a0, b1, acc[0][1], 0, 0, 0);
    acc[1][1] = __builtin_amdgcn_mfma_f32_16x16x32_bf16(a1, b1, acc[1][1], 0, 0, 0);
    a0 = na0; a1 = na1; b0 = nb0; b1 = nb1;
  }
  acc[0][0] = __builtin_amdgcn_mfma_f32_16x16x32_bf16(a0, b0, acc[0][0], 0, 0, 0);
  acc[1][0] = __builtin_amdgcn_mfma_f32_16x16x32_bf16(a1, b0, acc[1][0], 0, 0, 0);
  acc[0][1] = __builtin_amdgcn_mfma_f32_16x16x32_bf16(a0, b1, acc[0][1], 0, 0, 0);
  acc[1][1] = __builtin_amdgcn_mfma_f32_16x16x32_bf16(a1, b1, acc[1][1], 0, 0, 0);

  // epilogue: C/D layout col=lane&15, row=quad*4+reg; +bias, relu
  #pragma unroll
  for (int m = 0; m < 2; ++m) {
    #pragma unroll
    for (int j = 0; j < 2; ++j) {
      int col = w * 32 + j * 16 + l16;
      float bv = bias[col];
      #pragma unroll
      for (int rg = 0; rg < 4; ++rg) {
        int row = node0 + m * 16 + quad * 4 + rg;
        if (row < N_NODES) {
          float v = fmaxf(acc[m][j][rg] + bv, 0.f);
          if (OUT_BF16)
            ((uint16_t*)hout)[(size_t)row * HID + col] = f2bf(v);
          else
            ((float*)hout)[(size_t)row * HID + col] = v;
        }
      }
    }
  }
}

// ---------- pooling: 4 partial blocks per graph + tiny final ----------
__global__ __launch_bounds__(256) void k_poolpart(const float* __restrict__ h,
                                                  const int* __restrict__ gs, const int* __restrict__ ge,
                                                  float* __restrict__ psum) {
  __shared__ float red[HID];
  int g = blockIdx.x >> 2, p = blockIdx.x & 3;
  int c = threadIdx.x & 127, ph = threadIdx.x >> 7;
  int s = gs[g], e = ge[g];
  int len = e - s;
  int quarter = (len + 3) >> 2;
  int n0 = s + p * quarter;
  int n1 = min(n0 + quarter, e);
  float acc = 0.f;
  for (int n = n0 + ph; n < n1; n += 2) acc += h[(size_t)n * HID + c];
  if (ph == 1) red[c] = acc;
  __syncthreads();
  if (ph == 0 && n0 < n1) atomicAdd(&psum[g * HID + c], acc + red[c]);
}

__global__ __launch_bounds__(1024) void k_final(const float* __restrict__ psum,
                                                const int* __restrict__ gs, const int* __restrict__ ge,
                                                const float* __restrict__ linW, const float* __restrict__ linb,
                                                float* __restrict__ out) {
  int i = threadIdx.x;              // 64*16 = 1024
  int g = i >> 4, c = i & 15;
  float inv = 1.f / fmaxf((float)(ge[g] - gs[g]), 1.f);
  float s = 0.f;
  #pragma unroll 8
  for (int k = 0; k < HID; ++k) s += psum[g * HID + k] * linW[k * NUM_CLASSES + c];
  out[i] = s * inv + linb[c];
}

// ---------- launch ----------
extern "C" void kernel_launch(void* const* d_in, const int* in_sizes, int n_in,
                              void* d_out, int out_size, void* d_ws, size_t ws_size,
                              hipStream_t stream) {
  const float* x     = (const float*)d_in[0];
  const int*   ei    = (const int*)d_in[1];   // [2,E]: [0..E) src, [E..2E) dst
  const int*   et    = (const int*)d_in[2];
  const int*   batch = (const int*)d_in[3];
  const float* W1    = (const float*)d_in[4];
  const float* root1 = (const float*)d_in[5];
  const float* b1    = (const float*)d_in[6];
  const float* W2    = (const float*)d_in[7];
  const float* root2 = (const float*)d_in[8];
  const float* b2    = (const float*)d_in[9];
  const float* linW  = (const float*)d_in[10];
  const float* linb  = (const float*)d_in[11];
  float* out = (float*)d_out;

  char* ws = (char*)d_ws;
  size_t off = 0;
  auto alloc = [&](size_t bytes) -> char* {
    char* p = ws + off;
    off += (bytes + 255) & ~(size_t)255;
    return p;
  };
  // zero-region: deg8 | gb | psum (contiguous, one memset)
  int*      deg8  = (int*)alloc((size_t)N8 * 4);
  int*      gb    = (int*)alloc(2 * NUM_GRAPHS * 4);
  float*    psum  = (float*)alloc((size_t)NUM_GRAPHS * HID * 4);
  size_t zbytes = (size_t)N8 * 4 + 512 + (size_t)NUM_GRAPHS * HID * 4;
  int*      gs    = gb;
  int*      ge    = gb + NUM_GRAPHS;
  int*      offs8 = (int*)alloc((size_t)(N8 + 1) * 4);
  int*      nxt   = (int*)alloc((size_t)N8 * 4);
  int*      bsum  = (int*)alloc(512 * 4);
  uint32_t* epack = (uint32_t*)alloc((size_t)N_EDGES * 4);
  float*    wgt   = (float*)alloc((size_t)N_EDGES * 4);
  uint16_t* Wf1   = (uint16_t*)alloc((size_t)KOUT * KIN * 2);
  uint16_t* Wf2   = (uint16_t*)alloc((size_t)KOUT * KIN * 2);
  uint16_t* xb    = (uint16_t*)alloc((size_t)N_NODES * HID * 2);
  uint16_t* h1b   = (uint16_t*)alloc((size_t)N_NODES * HID * 2);
  float*    h2    = (float*)alloc((size_t)N_NODES * HID * 4);

  hipMemsetAsync(deg8, 0, zbytes, stream);

  int nb = (N8 + 1023) / 1024;          // 391 <= 512
  k_prep<<<HIST_B + BND_B + 2 * PW_B + CVT_B, 256, 0, stream>>>(
      ei, et, deg8, batch, gs, ge, W1, root1, Wf1, W2, root2, Wf2, x, xb);
  k_scan1<<<nb, 256, 0, stream>>>(deg8, offs8, bsum);
  k_scan2<<<1, 512, 0, stream>>>(bsum, nb);
  k_scan3<<<(N8 + 255) / 256, 256, 0, stream>>>(offs8, nxt, bsum);
  k_scatter<<<(N_EDGES + 255) / 256, 256, 0, stream>>>(ei, et, deg8, nxt, epack, wgt);

  // fused layers: aggregate(h) -> A[32,1152] in LDS -> MFMA with Wcat
  k_fused<true ><<<NBLK, 256, 0, stream>>>(xb,  epack, wgt, offs8, Wf1, b1, h1b);
  k_fused<false><<<NBLK, 256, 0, stream>>>(h1b, epack, wgt, offs8, Wf2, b2, h2);

  k_poolpart<<<4 * NUM_GRAPHS, 256, 0, stream>>>(h2, gs, ge, psum);
  k_final<<<1, 1024, 0, stream>>>(psum, gs, ge, linW, linb, out);
}

// Round 2
// 388.735 us; speedup vs baseline: 1.0529x; 1.0529x over previous
//
#include <hip/hip_runtime.h>
#include <hip/hip_bf16.h>
#include <stdint.h>

#define N_NODES 50000
#define N_EDGES 500000
#define R_REL 8
#define HID 128
#define KIN 128              // input features per slab
#define KOUT 1152            // 9*128: concat K dim (W_0..W_7 | root)
#define N8 400000            // N_NODES * R_REL composite buckets
#define NUM_GRAPHS 64
#define NUM_CLASSES 16

#define BN 32                // dst-nodes per fused block
#define LDA 1160             // A row stride in shorts (2320 B)
#define NKC 36               // K chunks of 32 (1152/32)
#define NBLK 1563            // ceil(50000/32)

typedef __attribute__((ext_vector_type(8))) short bf16x8;
typedef __attribute__((ext_vector_type(4))) float f32x4;

// ---------- helpers ----------
__device__ __forceinline__ uint16_t f2bf(float f) {
  uint32_t u = __float_as_uint(f);
  u += 0x7FFFu + ((u >> 16) & 1u);   // RNE
  return (uint16_t)(u >> 16);
}
__device__ __forceinline__ float bf2f(uint32_t b) {
  return __uint_as_float(b << 16);
}
__device__ __forceinline__ uint32_t pack2bf(float a, float b) {
  return (uint32_t)f2bf(a) | ((uint32_t)f2bf(b) << 16);
}

// ---------- merged prep: hist | bounds | prepw1 | prepw2 | x->bf16 ----------
#define HIST_B 1954
#define BND_B 196
#define PW_B 576            // KOUT*KIN / 256
#define CVT_B 3125          // N_NODES*HID/8 / 256
__global__ __launch_bounds__(256) void k_prep(const int* __restrict__ ei, const int* __restrict__ et,
                                              int* __restrict__ deg8,
                                              const int* __restrict__ batch,
                                              int* __restrict__ gs, int* __restrict__ ge,
                                              const float* __restrict__ W1, const float* __restrict__ root1,
                                              uint16_t* __restrict__ Wf1,
                                              const float* __restrict__ W2, const float* __restrict__ root2,
                                              uint16_t* __restrict__ Wf2,
                                              const float* __restrict__ x, uint16_t* __restrict__ xb) {
  int b = blockIdx.x;
  if (b < HIST_B) {                                 // edge histogram
    int i = b * 256 + threadIdx.x;
    if (i < N_EDGES) atomicAdd(&deg8[ei[N_EDGES + i] * R_REL + et[i]], 1);
    return;
  }
  b -= HIST_B;
  if (b < BND_B) {                                  // graph boundaries (batch sorted)
    int i = b * 256 + threadIdx.x;
    if (i < N_NODES) {
      int g = batch[i];
      if (i == 0) gs[g] = 0;
      else { int pg = batch[i - 1]; if (pg != g) { ge[pg] = i; gs[g] = i; } }
      if (i == N_NODES - 1) ge[g] = N_NODES;
    }
    return;
  }
  b -= BND_B;
  if (b < 2 * PW_B) {
    // prepw: Wf in B-frag order for K=1152 GEMM. frag f = kc*8 + nt (kc 0..35, nt 0..7).
    // lane L=(quad,l16), elem e: B[kk = kc*32+quad*8+e][col = nt*16+l16], kk -> slab s=kk>>7, k=kk&127
    const float* W    = (b < PW_B) ? W1 : W2;
    const float* root = (b < PW_B) ? root1 : root2;
    uint16_t*    Wf   = (b < PW_B) ? Wf1 : Wf2;
    int idx = (b % PW_B) * 256 + threadIdx.x;       // over KOUT*KIN
    int e = idx & 7, L = (idx >> 3) & 63, f = idx >> 9;
    int quad = L >> 4, l16 = L & 15;
    int nt = f & 7, kc = f >> 3;
    int kk = kc * 32 + quad * 8 + e;
    int s = kk >> 7, k = kk & 127;
    int col = nt * 16 + l16;
    float v = (s < R_REL) ? W[((size_t)s * KIN + k) * HID + col] : root[(size_t)k * HID + col];
    Wf[idx] = f2bf(v);
    return;
  }
  b -= 2 * PW_B;
  {                                                 // x (fp32) -> xb (bf16), 8 elems/thread
    int i = b * 256 + threadIdx.x;                  // < 800000 exact
    const float4* p = (const float4*)x + (size_t)i * 2;
    float4 a = p[0], c = p[1];
    uint4 o;
    o.x = pack2bf(a.x, a.y); o.y = pack2bf(a.z, a.w);
    o.z = pack2bf(c.x, c.y); o.w = pack2bf(c.z, c.w);
    *(uint4*)(xb + (size_t)i * 8) = o;
  }
}

// ---------- scans ----------
__global__ __launch_bounds__(256) void k_scan1(const int* __restrict__ deg8, int* __restrict__ offs8,
                                               int* __restrict__ bsum) {
  __shared__ int sh[256];
  int t = threadIdx.x;
  int base = blockIdx.x * 1024 + t * 4;
  int v[4]; int s = 0;
  #pragma unroll
  for (int i = 0; i < 4; ++i) { int idx = base + i; v[i] = (idx < N8) ? deg8[idx] : 0; s += v[i]; }
  sh[t] = s;
  __syncthreads();
  for (int d = 1; d < 256; d <<= 1) {
    int add = (t >= d) ? sh[t - d] : 0;
    __syncthreads();
    sh[t] += add;
    __syncthreads();
  }
  int run = sh[t] - s;
  if (t == 255) bsum[blockIdx.x] = sh[255];
  #pragma unroll
  for (int i = 0; i < 4; ++i) { int idx = base + i; if (idx < N8) offs8[idx] = run; run += v[i]; }
}

__global__ __launch_bounds__(512) void k_scan2(int* __restrict__ bsum, int nb) {
  __shared__ int sh[512];
  int t = threadIdx.x;
  int v = (t < nb) ? bsum[t] : 0;
  sh[t] = v;
  __syncthreads();
  for (int d = 1; d < 512; d <<= 1) {
    int add = (t >= d) ? sh[t - d] : 0;
    __syncthreads();
    sh[t] += add;
    __syncthreads();
  }
  if (t < nb) bsum[t] = sh[t] - v;   // exclusive
}

__global__ __launch_bounds__(256) void k_scan3(int* __restrict__ offs8, int* __restrict__ nxt,
                                               const int* __restrict__ bsum) {
  int i = blockIdx.x * 256 + threadIdx.x;
  if (i < N8) {
    int o = offs8[i] + bsum[i >> 10];
    offs8[i] = o;
    nxt[i] = o;
  }
  if (i == 0) offs8[N8] = N_EDGES;
}

// scatter: place edge; emit packed (src | rel<<16). Weight (1/cnt) now applied at
// flush time in k_fused by counting the group, so no wgt array and no deg8 read.
__global__ __launch_bounds__(256) void k_scatter(const int* __restrict__ ei, const int* __restrict__ et,
                                                 int* __restrict__ nxt, uint32_t* __restrict__ epack) {
  int i = blockIdx.x * 256 + threadIdx.x;
  if (i < N_EDGES) {
    int rel = et[i];
    int key = ei[N_EDGES + i] * R_REL + rel;
    int p = atomicAdd(&nxt[key], 1);
    epack[p] = (uint32_t)ei[i] | ((uint32_t)rel << 16);   // src < 2^16
  }
}

// ---------- fused layer: aggregate-then-transform ----------
// Block = 32 dst nodes, 512 threads (8 waves), LDS A[32][1160] bf16 (74240 B).
// 2 blocks/CU -> 16 waves/CU (4/SIMD), VGPR capped at 128 by launch_bounds.
// Phase 1: wave w aggregates nodes w*4..w*4+4. Per node: 16-deep gather batches,
//          unweighted fp32 accumulate per rel-group (edges (dst,rel)-sorted),
//          scale by 1/cnt at flush. Root slab = own h.
// Phase 2: out[32,128] = A[32,1152] @ Wcat; wave w owns cols [w*16, w*16+16),
//          depth-2 prefetch on B (global/L2) and A (LDS).
template<bool OUT_BF16>
__global__ __launch_bounds__(512, 4) void k_fused(const uint16_t* __restrict__ hin,
                                                  const uint32_t* __restrict__ epack,
                                                  const int* __restrict__ offs8,
                                                  const uint16_t* __restrict__ Wf,
                                                  const float* __restrict__ bias,
                                                  void* __restrict__ hout) {
  __shared__ __align__(16) uint16_t As[BN * LDA];
  int t = threadIdx.x;
  int w = __builtin_amdgcn_readfirstlane(t >> 6);
  int L = t & 63;
  int quad = L >> 4, l16 = L & 15;
  int node0 = blockIdx.x * BN;

  // zero A tile: 32*1160 = 37120 shorts = 4640 b128 chunks over 512 threads
  {
    bf16x8 z = 0;
    #pragma unroll
    for (int i = 0; i < 9; ++i) ((bf16x8*)As)[i * 512 + t] = z;
    if (t < 32) ((bf16x8*)As)[9 * 512 + t] = z;
  }

  // cooperative offs8 preload for this wave's 4 nodes: 33 consecutive ints, lane-loaded
  int obase = (node0 + w * 4) * R_REL;
  int offv = offs8[min(obase + L, N8)];

  // hoist first two B-frag loads: in flight across the whole aggregation phase
  const uint16_t* wp = Wf + (size_t)w * 512 + (size_t)L * 8;
  bf16x8 bA = *(const bf16x8*)(wp);
  bf16x8 bB = *(const bf16x8*)(wp + 4096);

  __syncthreads();

  // ---- phase 1: aggregation (wave per node, lane = 2 dims) ----
  #pragma unroll 1
  for (int ni = 0; ni < 4; ++ni) {
    int nl = w * 4 + ni;
    int n = node0 + nl;
    if (n >= N_NODES) break;
    uint16_t* Arow = As + nl * LDA;
    // root slab (s=8): direct bf16 copy of own features
    *(uint32_t*)(Arow + R_REL * HID + L * 2) =
        *(const uint32_t*)(hin + (size_t)n * HID + L * 2);
    int o0 = __builtin_amdgcn_readlane(offv, ni * 8);
    int o8 = __builtin_amdgcn_readlane(offv, ni * 8 + 8);
    float ax = 0.f, ay = 0.f;
    int cur = -1, cnt = 0;
    #pragma unroll 1
    for (int g = o0; g < o8; g += 16) {
      int m = min(16, o8 - g);
      uint32_t pv[16], vv[16];
      #pragma unroll
      for (int i = 0; i < 16; ++i) if (i < m) pv[i] = epack[g + i];
      #pragma unroll
      for (int i = 0; i < 16; ++i) if (i < m)
        vv[i] = *(const uint32_t*)(hin + (size_t)(pv[i] & 0xFFFFu) * HID + L * 2);
      #pragma unroll
      for (int i = 0; i < 16; ++i) if (i < m) {
        int r = __builtin_amdgcn_readfirstlane((int)(pv[i] >> 16));  // wave-uniform -> scalar branch
        if (r != cur) {                        // (dst,rel)-sorted: flush finished group
          if (cur >= 0) {
            float inv = 1.0f / (float)cnt;
            *(uint32_t*)(Arow + cur * HID + L * 2) = pack2bf(ax * inv, ay * inv);
          }
          ax = 0.f; ay = 0.f; cnt = 0; cur = r;
        }
        ax += bf2f(vv[i] & 0xFFFFu);
        ay += bf2f(vv[i] >> 16);
        ++cnt;
      }
    }
    if (cur >= 0) {
      float inv = 1.0f / (float)cnt;
      *(uint32_t*)(Arow + cur * HID + L * 2) = pack2bf(ax * inv, ay * inv);
    }
  }
  __syncthreads();

  // ---- phase 2: GEMM. wave w: rows 0..32 (2 m-frags) x cols [w*16, w*16+16) ----
  f32x4 acc0 = (f32x4){0.f, 0.f, 0.f, 0.f};
  f32x4 acc1 = (f32x4){0.f, 0.f, 0.f, 0.f};
  const uint16_t* ap = As + l16 * LDA + quad * 8;   // A[m*16+l16][kc*32+quad*8+e]

  bf16x8 aA0 = *(const bf16x8*)(ap);
  bf16x8 aA1 = *(const bf16x8*)(ap + 16 * LDA);
  bf16x8 aB0 = *(const bf16x8*)(ap + 32);
  bf16x8 aB1 = *(const bf16x8*)(ap + 32 + 16 * LDA);

  #pragma unroll 1
  for (int kc = 0; kc < NKC - 2; kc += 2) {
    bf16x8 nb  = *(const bf16x8*)(wp + (size_t)(kc + 2) * 4096);
    bf16x8 n0  = *(const bf16x8*)(ap + (kc + 2) * 32);
    bf16x8 n1  = *(const bf16x8*)(ap + (kc + 2) * 32 + 16 * LDA);
    acc0 = __builtin_amdgcn_mfma_f32_16x16x32_bf16(aA0, bA, acc0, 0, 0, 0);
    acc1 = __builtin_amdgcn_mfma_f32_16x16x32_bf16(aA1, bA, acc1, 0, 0, 0);
    bA = nb; aA0 = n0; aA1 = n1;
    nb = *(const bf16x8*)(wp + (size_t)(kc + 3) * 4096);
    n0 = *(const bf16x8*)(ap + (kc + 3) * 32);
    n1 = *(const bf16x8*)(ap + (kc + 3) * 32 + 16 * LDA);
    acc0 = __builtin_amdgcn_mfma_f32_16x16x32_bf16(aB0, bB, acc0, 0, 0, 0);
    acc1 = __builtin_amdgcn_mfma_f32_16x16x32_bf16(aB1, bB, acc1, 0, 0, 0);
    bB = nb; aB0 = n0; aB1 = n1;
  }
  acc0 = __builtin_amdgcn_mfma_f32_16x16x32_bf16(aA0, bA, acc0, 0, 0, 0);
  acc1 = __builtin_amdgcn_mfma_f32_16x16x32_bf16(aA1, bA, acc1, 0, 0, 0);
  acc0 = __builtin_amdgcn_mfma_f32_16x16x32_bf16(aB0, bB, acc0, 0, 0, 0);
  acc1 = __builtin_amdgcn_mfma_f32_16x16x32_bf16(aB1, bB, acc1, 0, 0, 0);

  // epilogue: C/D layout col=lane&15, row=quad*4+reg; +bias, relu
  {
    int col = w * 16 + l16;
    float bv = bias[col];
    #pragma unroll
    for (int rg = 0; rg < 4; ++rg) {
      int row = node0 + quad * 4 + rg;
      if (row < N_NODES) {
        float v = fmaxf(acc0[rg] + bv, 0.f);
        if (OUT_BF16) ((uint16_t*)hout)[(size_t)row * HID + col] = f2bf(v);
        else          ((float*)hout)[(size_t)row * HID + col] = v;
      }
    }
    #pragma unroll
    for (int rg = 0; rg < 4; ++rg) {
      int row = node0 + 16 + quad * 4 + rg;
      if (row < N_NODES) {
        float v = fmaxf(acc1[rg] + bv, 0.f);
        if (OUT_BF16) ((uint16_t*)hout)[(size_t)row * HID + col] = f2bf(v);
        else          ((float*)hout)[(size_t)row * HID + col] = v;
      }
    }
  }
}

// ---------- pooling: 4 partial blocks per graph + tiny final ----------
__global__ __launch_bounds__(256) void k_poolpart(const float* __restrict__ h,
                                                  const int* __restrict__ gs, const int* __restrict__ ge,
                                                  float* __restrict__ psum) {
  __shared__ float red[HID];
  int g = blockIdx.x >> 2, p = blockIdx.x & 3;
  int c = threadIdx.x & 127, ph = threadIdx.x >> 7;
  int s = gs[g], e = ge[g];
  int len = e - s;
  int quarter = (len + 3) >> 2;
  int n0 = s + p * quarter;
  int n1 = min(n0 + quarter, e);
  float acc = 0.f;
  for (int n = n0 + ph; n < n1; n += 2) acc += h[(size_t)n * HID + c];
  if (ph == 1) red[c] = acc;
  __syncthreads();
  if (ph == 0 && n0 < n1) atomicAdd(&psum[g * HID + c], acc + red[c]);
}

__global__ __launch_bounds__(1024) void k_final(const float* __restrict__ psum,
                                                const int* __restrict__ gs, const int* __restrict__ ge,
                                                const float* __restrict__ linW, const float* __restrict__ linb,
                                                float* __restrict__ out) {
  int i = threadIdx.x;              // 64*16 = 1024
  int g = i >> 4, c = i & 15;
  float inv = 1.f / fmaxf((float)(ge[g] - gs[g]), 1.f);
  float s = 0.f;
  #pragma unroll 8
  for (int k = 0; k < HID; ++k) s += psum[g * HID + k] * linW[k * NUM_CLASSES + c];
  out[i] = s * inv + linb[c];
}

// ---------- launch ----------
extern "C" void kernel_launch(void* const* d_in, const int* in_sizes, int n_in,
                              void* d_out, int out_size, void* d_ws, size_t ws_size,
                              hipStream_t stream) {
  const float* x     = (const float*)d_in[0];
  const int*   ei    = (const int*)d_in[1];   // [2,E]: [0..E) src, [E..2E) dst
  const int*   et    = (const int*)d_in[2];
  const int*   batch = (const int*)d_in[3];
  const float* W1    = (const float*)d_in[4];
  const float* root1 = (const float*)d_in[5];
  const float* b1    = (const float*)d_in[6];
  const float* W2    = (const float*)d_in[7];
  const float* root2 = (const float*)d_in[8];
  const float* b2    = (const float*)d_in[9];
  const float* linW  = (const float*)d_in[10];
  const float* linb  = (const float*)d_in[11];
  float* out = (float*)d_out;

  char* ws = (char*)d_ws;
  size_t off = 0;
  auto alloc = [&](size_t bytes) -> char* {
    char* p = ws + off;
    off += (bytes + 255) & ~(size_t)255;
    return p;
  };
  // zero-region: deg8 | gb | psum (contiguous, one memset)
  int*      deg8  = (int*)alloc((size_t)N8 * 4);
  int*      gb    = (int*)alloc(2 * NUM_GRAPHS * 4);
  float*    psum  = (float*)alloc((size_t)NUM_GRAPHS * HID * 4);
  size_t zbytes = (size_t)N8 * 4 + 512 + (size_t)NUM_GRAPHS * HID * 4;
  int*      gs    = gb;
  int*      ge    = gb + NUM_GRAPHS;
  int*      offs8 = (int*)alloc((size_t)(N8 + 1) * 4);
  int*      nxt   = (int*)alloc((size_t)N8 * 4);
  int*      bsum  = (int*)alloc(512 * 4);
  uint32_t* epack = (uint32_t*)alloc((size_t)N_EDGES * 4);
  uint16_t* Wf1   = (uint16_t*)alloc((size_t)KOUT * KIN * 2);
  uint16_t* Wf2   = (uint16_t*)alloc((size_t)KOUT * KIN * 2);
  uint16_t* xb    = (uint16_t*)alloc((size_t)N_NODES * HID * 2);
  uint16_t* h1b   = (uint16_t*)alloc((size_t)N_NODES * HID * 2);
  float*    h2    = (float*)alloc((size_t)N_NODES * HID * 4);

  hipMemsetAsync(deg8, 0, zbytes, stream);

  int nb = (N8 + 1023) / 1024;          // 391 <= 512
  k_prep<<<HIST_B + BND_B + 2 * PW_B + CVT_B, 256, 0, stream>>>(
      ei, et, deg8, batch, gs, ge, W1, root1, Wf1, W2, root2, Wf2, x, xb);
  k_scan1<<<nb, 256, 0, stream>>>(deg8, offs8, bsum);
  k_scan2<<<1, 512, 0, stream>>>(bsum, nb);
  k_scan3<<<(N8 + 255) / 256, 256, 0, stream>>>(offs8, nxt, bsum);
  k_scatter<<<(N_EDGES + 255) / 256, 256, 0, stream>>>(ei, et, nxt, epack);

  // fused layers: aggregate(h) -> A[32,1152] in LDS -> MFMA with Wcat
  k_fused<true ><<<NBLK, 512, 0, stream>>>(xb,  epack, offs8, Wf1, b1, h1b);
  k_fused<false><<<NBLK, 512, 0, stream>>>(h1b, epack, offs8, Wf2, b2, h2);

  k_poolpart<<<4 * NUM_GRAPHS, 256, 0, stream>>>(h2, gs, ge, psum);
  k_final<<<1, 1024, 0, stream>>>(psum, gs, ge, linW, linb, out);
}

// Round 3
// 316.716 us; speedup vs baseline: 1.2924x; 1.2274x over previous
//
#include <hip/hip_runtime.h>
#include <hip/hip_bf16.h>
#include <stdint.h>

#define N_NODES 50000
#define N_EDGES 500000
#define R_REL 8
#define HID 128
#define KIN 128              // input features per slab
#define KOUT 1152            // 9*128: concat K dim (W_0..W_7 | root)
#define NUM_GRAPHS 64
#define NUM_CLASSES 16

#define BN 32                // dst-nodes per fused block
#define LDA 1160             // A row stride in shorts (2320 B)
#define NKC 36               // K chunks of 32 (1152/32)
#define NBLK 1563            // ceil(50000/32)

typedef __attribute__((ext_vector_type(8))) short bf16x8;
typedef __attribute__((ext_vector_type(4))) float f32x4;

// ---------- helpers ----------
__device__ __forceinline__ uint16_t f2bf(float f) {
  uint32_t u = __float_as_uint(f);
  u += 0x7FFFu + ((u >> 16) & 1u);   // RNE
  return (uint16_t)(u >> 16);
}
__device__ __forceinline__ float bf2f(uint32_t b) {
  return __uint_as_float(b << 16);
}
__device__ __forceinline__ uint32_t pack2bf(float a, float b) {
  return (uint32_t)f2bf(a) | ((uint32_t)f2bf(b) << 16);
}

// ---------- merged prep: hist | bounds | prepw1 | prepw2 | x->bf16 ----------
#define HIST_B 1954
#define BND_B 196
#define PW_B 576            // KOUT*KIN / 256
#define CVT_B 3125          // N_NODES*HID/8 / 256
__global__ __launch_bounds__(256) void k_prep(const int* __restrict__ ei, const int* __restrict__ et,
                                              int* __restrict__ deg,
                                              const int* __restrict__ batch,
                                              int* __restrict__ gs, int* __restrict__ ge,
                                              const float* __restrict__ W1, const float* __restrict__ root1,
                                              uint16_t* __restrict__ Wf1,
                                              const float* __restrict__ W2, const float* __restrict__ root2,
                                              uint16_t* __restrict__ Wf2,
                                              const float* __restrict__ x, uint16_t* __restrict__ xb) {
  int b = blockIdx.x;
  if (b < HIST_B) {                                 // per-dst edge histogram (50K buckets)
    int i = b * 256 + threadIdx.x;
    if (i < N_EDGES) atomicAdd(&deg[ei[N_EDGES + i]], 1);
    return;
  }
  b -= HIST_B;
  if (b < BND_B) {                                  // graph boundaries (batch sorted)
    int i = b * 256 + threadIdx.x;
    if (i < N_NODES) {
      int g = batch[i];
      if (i == 0) gs[g] = 0;
      else { int pg = batch[i - 1]; if (pg != g) { ge[pg] = i; gs[g] = i; } }
      if (i == N_NODES - 1) ge[g] = N_NODES;
    }
    return;
  }
  b -= BND_B;
  if (b < 2 * PW_B) {
    // prepw: Wf in B-frag order for K=1152 GEMM. frag f = kc*8 + nt (kc 0..35, nt 0..7).
    // lane L=(quad,l16), elem e: B[kk = kc*32+quad*8+e][col = nt*16+l16], kk -> slab s=kk>>7, k=kk&127
    const float* W    = (b < PW_B) ? W1 : W2;
    const float* root = (b < PW_B) ? root1 : root2;
    uint16_t*    Wf   = (b < PW_B) ? Wf1 : Wf2;
    int idx = (b % PW_B) * 256 + threadIdx.x;       // over KOUT*KIN
    int e = idx & 7, L = (idx >> 3) & 63, f = idx >> 9;
    int quad = L >> 4, l16 = L & 15;
    int nt = f & 7, kc = f >> 3;
    int kk = kc * 32 + quad * 8 + e;
    int s = kk >> 7, k = kk & 127;
    int col = nt * 16 + l16;
    float v = (s < R_REL) ? W[((size_t)s * KIN + k) * HID + col] : root[(size_t)k * HID + col];
    Wf[idx] = f2bf(v);
    return;
  }
  b -= 2 * PW_B;
  {                                                 // x (fp32) -> xb (bf16), 8 elems/thread
    int i = b * 256 + threadIdx.x;                  // < 800000 exact
    const float4* p = (const float4*)x + (size_t)i * 2;
    float4 a = p[0], c = p[1];
    uint4 o;
    o.x = pack2bf(a.x, a.y); o.y = pack2bf(a.z, a.w);
    o.z = pack2bf(c.x, c.y); o.w = pack2bf(c.z, c.w);
    *(uint4*)(xb + (size_t)i * 8) = o;
  }
}

// ---------- scans over 50K dst buckets ----------
__global__ __launch_bounds__(256) void k_scan1(const int* __restrict__ deg, int* __restrict__ offs,
                                               int* __restrict__ bsum) {
  __shared__ int sh[256];
  int t = threadIdx.x;
  int base = blockIdx.x * 1024 + t * 4;
  int v[4]; int s = 0;
  #pragma unroll
  for (int i = 0; i < 4; ++i) { int idx = base + i; v[i] = (idx < N_NODES) ? deg[idx] : 0; s += v[i]; }
  sh[t] = s;
  __syncthreads();
  for (int d = 1; d < 256; d <<= 1) {
    int add = (t >= d) ? sh[t - d] : 0;
    __syncthreads();
    sh[t] += add;
    __syncthreads();
  }
  int run = sh[t] - s;
  if (t == 255) bsum[blockIdx.x] = sh[255];
  #pragma unroll
  for (int i = 0; i < 4; ++i) { int idx = base + i; if (idx < N_NODES) offs[idx] = run; run += v[i]; }
}

__global__ __launch_bounds__(512) void k_scan2(int* __restrict__ bsum, int nb) {
  __shared__ int sh[512];
  int t = threadIdx.x;
  int v = (t < nb) ? bsum[t] : 0;
  sh[t] = v;
  __syncthreads();
  for (int d = 1; d < 512; d <<= 1) {
    int add = (t >= d) ? sh[t - d] : 0;
    __syncthreads();
    sh[t] += add;
    __syncthreads();
  }
  if (t < nb) bsum[t] = sh[t] - v;   // exclusive
}

__global__ __launch_bounds__(256) void k_scan3(int* __restrict__ offs, int* __restrict__ nxt,
                                               const int* __restrict__ bsum) {
  int i = blockIdx.x * 256 + threadIdx.x;
  if (i < N_NODES) {
    int o = offs[i] + bsum[i >> 10];
    offs[i] = o;
    nxt[i] = o;
  }
  if (i == 0) offs[N_NODES] = N_EDGES;
}

// scatter: bucket edges by dst; epack = src | rel<<16
__global__ __launch_bounds__(256) void k_scatter(const int* __restrict__ ei, const int* __restrict__ et,
                                                 int* __restrict__ nxt, uint32_t* __restrict__ epack) {
  int i = blockIdx.x * 256 + threadIdx.x;
  if (i < N_EDGES) {
    int rel = et[i];
    int key = ei[N_EDGES + i];
    int p = atomicAdd(&nxt[key], 1);
    epack[p] = (uint32_t)ei[i] | ((uint32_t)rel << 16);   // src < 2^16
  }
}

// ---------- fused layer: aggregate-then-transform ----------
// Block = 32 dst nodes, 512 threads (8 waves), LDS A[32][1160] bf16 (74240 B, 2 blocks/CU).
// Phase 1: wave w aggregates nodes w*4..w*4+4 as ONE flat edge stream [offs[n0],offs[n0+4]).
//   16-deep batches; epack word readfirstlane'd -> SGPR-based gather addressing; per-rel
//   fp32 register accumulators dispatched by scalar branch tree; one flush per node.
// Phase 2: out[32,128] = A[32,1152] @ Wcat; wave w owns cols [w*16,w*16+16); depth-4 B prefetch.
// MODE 0: write bf16 hout. MODE 1: fused global-mean-pool partials into psum (no hout).
template<int MODE>
__global__ __launch_bounds__(512, 4) void k_fused(const uint16_t* __restrict__ hin,
                                                  const uint32_t* __restrict__ epack,
                                                  const int* __restrict__ offs,
                                                  const uint16_t* __restrict__ Wf,
                                                  const float* __restrict__ bias,
                                                  void* __restrict__ hout,
                                                  float* __restrict__ psum,
                                                  const int* __restrict__ batch) {
  __shared__ __align__(16) uint16_t As[BN * LDA];
  int t = threadIdx.x;
  int w = __builtin_amdgcn_readfirstlane(t >> 6);
  int L = t & 63;
  int quad = L >> 4, l16 = L & 15;
  int node0 = blockIdx.x * BN;

  // zero A tile: 32*1160 = 37120 shorts = 4640 b128 chunks over 512 threads
  {
    bf16x8 z = 0;
    #pragma unroll
    for (int i = 0; i < 9; ++i) ((bf16x8*)As)[i * 512 + t] = z;
    if (t < 32) ((bf16x8*)As)[9 * 512 + t] = z;
  }

  // block-wide offs preload: lanes 0..32 hold offs[node0 .. node0+32]
  int offv = offs[min(node0 + min(L, 32), N_NODES)];

  // hoist depth-4 B prefetch across the aggregation phase (same addrs every block: L2-hot)
  const uint16_t* wp = Wf + (size_t)w * 512 + (size_t)L * 8;
  bf16x8 b0 = *(const bf16x8*)(wp);
  bf16x8 b1 = *(const bf16x8*)(wp + 1 * 4096);
  bf16x8 b2 = *(const bf16x8*)(wp + 2 * 4096);
  bf16x8 b3 = *(const bf16x8*)(wp + 3 * 4096);

  __syncthreads();

  // ---- phase 1: aggregation ----
  {
    // root slabs upfront (independent coalesced loads, overlap with edge stream)
    #pragma unroll
    for (int ni = 0; ni < 4; ++ni) {
      int n = node0 + w * 4 + ni;
      if (n < N_NODES)
        *(uint32_t*)(As + (w * 4 + ni) * LDA + R_REL * HID + L * 2) =
            *(const uint32_t*)(hin + (size_t)n * HID + L * 2);
    }

    float ax[8] = {0,0,0,0,0,0,0,0}, ay[8] = {0,0,0,0,0,0,0,0};
    int cn[8] = {0,0,0,0,0,0,0,0};

    int o0   = __builtin_amdgcn_readlane(offv, w * 4);
    int oEnd = __builtin_amdgcn_readlane(offv, w * 4 + 4);
    int curb = 0;
    int nbound = __builtin_amdgcn_readlane(offv, w * 4 + 1);

    auto FLUSH = [&](int nl) {
      uint16_t* Ar = As + nl * LDA;
      #pragma unroll
      for (int r = 0; r < 8; ++r) {
        if (cn[r]) {
          float iv = 1.0f / (float)cn[r];
          *(uint32_t*)(Ar + r * HID + L * 2) = pack2bf(ax[r] * iv, ay[r] * iv);
          ax[r] = 0.f; ay[r] = 0.f; cn[r] = 0;
        }
      }
    };

    #pragma unroll 1
    for (int g = o0; g < oEnd; g += 16) {
      int m = min(16, oEnd - g);
      uint32_t pvv[16], sv[16], vv[16];
      #pragma unroll
      for (int i = 0; i < 16; ++i) if (i < m) pvv[i] = epack[g + i];
      #pragma unroll
      for (int i = 0; i < 16; ++i) if (i < m) {
        uint32_t ps = __builtin_amdgcn_readfirstlane(pvv[i]);   // SGPR
        sv[i] = ps;
        const uint16_t* bp = hin + (size_t)(ps & 0xFFFFu) * HID;  // uniform base
        vv[i] = *(const uint32_t*)(bp + 2u * (uint32_t)L);        // saddr + L*4B
      }
      #pragma unroll
      for (int i = 0; i < 16; ++i) if (i < m) {
        int e = g + i;
        while (e >= nbound) {                 // node boundary: flush finished node
          FLUSH(w * 4 + curb);
          ++curb;
          nbound = __builtin_amdgcn_readlane(offv, w * 4 + curb + 1);
        }
        uint32_t v = vv[i];
        float lo = bf2f(v & 0xFFFFu), hi = bf2f(v >> 16);
        uint32_t r = sv[i] >> 16;             // wave-uniform -> scalar branch tree
        if (r < 4) {
          if (r < 2) { if (r == 0) { ax[0]+=lo; ay[0]+=hi; ++cn[0]; } else { ax[1]+=lo; ay[1]+=hi; ++cn[1]; } }
          else       { if (r == 2) { ax[2]+=lo; ay[2]+=hi; ++cn[2]; } else { ax[3]+=lo; ay[3]+=hi; ++cn[3]; } }
        } else {
          if (r < 6) { if (r == 4) { ax[4]+=lo; ay[4]+=hi; ++cn[4]; } else { ax[5]+=lo; ay[5]+=hi; ++cn[5]; } }
          else       { if (r == 6) { ax[6]+=lo; ay[6]+=hi; ++cn[6]; } else { ax[7]+=lo; ay[7]+=hi; ++cn[7]; } }
        }
      }
    }
    FLUSH(w * 4 + curb);
  }
  __syncthreads();

  // ---- phase 2: GEMM. wave w: rows 0..32 (2 m-frags) x cols [w*16, w*16+16) ----
  f32x4 acc0 = (f32x4){0.f, 0.f, 0.f, 0.f};
  f32x4 acc1 = (f32x4){0.f, 0.f, 0.f, 0.f};
  const uint16_t* ap = As + l16 * LDA + quad * 8;   // A[m*16+l16][kc*32+quad*8+e]

  bf16x8 a0 = *(const bf16x8*)(ap);
  bf16x8 a1 = *(const bf16x8*)(ap + 16 * LDA);

  #pragma unroll 1
  for (int kc = 0; kc < 32; kc += 4) {
    bf16x8 n0, n1, nb;
    // j=0: consume b0 (=B[kc]), prefetch B[kc+4], A[kc+1]
    n0 = *(const bf16x8*)(ap + (kc + 1) * 32);
    n1 = *(const bf16x8*)(ap + (kc + 1) * 32 + 16 * LDA);
    nb = *(const bf16x8*)(wp + (size_t)(kc + 4) * 4096);
    acc0 = __builtin_amdgcn_mfma_f32_16x16x32_bf16(a0, b0, acc0, 0, 0, 0);
    acc1 = __builtin_amdgcn_mfma_f32_16x16x32_bf16(a1, b0, acc1, 0, 0, 0);
    a0 = n0; a1 = n1; b0 = nb;
    // j=1
    n0 = *(const bf16x8*)(ap + (kc + 2) * 32);
    n1 = *(const bf16x8*)(ap + (kc + 2) * 32 + 16 * LDA);
    nb = *(const bf16x8*)(wp + (size_t)(kc + 5) * 4096);
    acc0 = __builtin_amdgcn_mfma_f32_16x16x32_bf16(a0, b1, acc0, 0, 0, 0);
    acc1 = __builtin_amdgcn_mfma_f32_16x16x32_bf16(a1, b1, acc1, 0, 0, 0);
    a0 = n0; a1 = n1; b1 = nb;
    // j=2
    n0 = *(const bf16x8*)(ap + (kc + 3) * 32);
    n1 = *(const bf16x8*)(ap + (kc + 3) * 32 + 16 * LDA);
    nb = *(const bf16x8*)(wp + (size_t)(kc + 6) * 4096);
    acc0 = __builtin_amdgcn_mfma_f32_16x16x32_bf16(a0, b2, acc0, 0, 0, 0);
    acc1 = __builtin_amdgcn_mfma_f32_16x16x32_bf16(a1, b2, acc1, 0, 0, 0);
    a0 = n0; a1 = n1; b2 = nb;
    // j=3
    n0 = *(const bf16x8*)(ap + (kc + 4) * 32);
    n1 = *(const bf16x8*)(ap + (kc + 4) * 32 + 16 * LDA);
    nb = *(const bf16x8*)(wp + (size_t)(kc + 7) * 4096);
    acc0 = __builtin_amdgcn_mfma_f32_16x16x32_bf16(a0, b3, acc0, 0, 0, 0);
    acc1 = __builtin_amdgcn_mfma_f32_16x16x32_bf16(a1, b3, acc1, 0, 0, 0);
    a0 = n0; a1 = n1; b3 = nb;
  }
  // tail kc = 32..35 (b0..b3 = B[32..35], a = A[32])
  {
    bf16x8 n0, n1;
    n0 = *(const bf16x8*)(ap + 33 * 32);
    n1 = *(const bf16x8*)(ap + 33 * 32 + 16 * LDA);
    acc0 = __builtin_amdgcn_mfma_f32_16x16x32_bf16(a0, b0, acc0, 0, 0, 0);
    acc1 = __builtin_amdgcn_mfma_f32_16x16x32_bf16(a1, b0, acc1, 0, 0, 0);
    a0 = n0; a1 = n1;
    n0 = *(const bf16x8*)(ap + 34 * 32);
    n1 = *(const bf16x8*)(ap + 34 * 32 + 16 * LDA);
    acc0 = __builtin_amdgcn_mfma_f32_16x16x32_bf16(a0, b1, acc0, 0, 0, 0);
    acc1 = __builtin_amdgcn_mfma_f32_16x16x32_bf16(a1, b1, acc1, 0, 0, 0);
    a0 = n0; a1 = n1;
    n0 = *(const bf16x8*)(ap + 35 * 32);
    n1 = *(const bf16x8*)(ap + 35 * 32 + 16 * LDA);
    acc0 = __builtin_amdgcn_mfma_f32_16x16x32_bf16(a0, b2, acc0, 0, 0, 0);
    acc1 = __builtin_amdgcn_mfma_f32_16x16x32_bf16(a1, b2, acc1, 0, 0, 0);
    a0 = n0; a1 = n1;
    acc0 = __builtin_amdgcn_mfma_f32_16x16x32_bf16(a0, b3, acc0, 0, 0, 0);
    acc1 = __builtin_amdgcn_mfma_f32_16x16x32_bf16(a1, b3, acc1, 0, 0, 0);
  }

  // ---- epilogue: C/D layout col=lane&15, row=quad*4+reg ----
  int col = w * 16 + l16;
  float bv = bias[col];
  if (MODE == 0) {
    #pragma unroll
    for (int rg = 0; rg < 4; ++rg) {
      int row = node0 + quad * 4 + rg;
      if (row < N_NODES)
        ((uint16_t*)hout)[(size_t)row * HID + col] = f2bf(fmaxf(acc0[rg] + bv, 0.f));
    }
    #pragma unroll
    for (int rg = 0; rg < 4; ++rg) {
      int row = node0 + 16 + quad * 4 + rg;
      if (row < N_NODES)
        ((uint16_t*)hout)[(size_t)row * HID + col] = f2bf(fmaxf(acc1[rg] + bv, 0.f));
    }
  } else {
    // fused global-mean-pool partials (sum; divide in k_final)
    bool fast = false;
    int gA = 0;
    if (node0 + BN <= N_NODES) {
      gA = batch[node0];
      int gB = batch[node0 + BN - 1];
      fast = (gA == gB);
    }
    if (fast) {
      float s = 0.f;
      #pragma unroll
      for (int rg = 0; rg < 4; ++rg) s += fmaxf(acc0[rg] + bv, 0.f);
      #pragma unroll
      for (int rg = 0; rg < 4; ++rg) s += fmaxf(acc1[rg] + bv, 0.f);
      s += __shfl_xor(s, 16);
      s += __shfl_xor(s, 32);
      if (quad == 0) atomicAdd(&psum[gA * HID + col], s);
    } else {
      int gp = -1; float run = 0.f;
      #pragma unroll
      for (int k = 0; k < 8; ++k) {
        int rg = k & 3;
        int row = node0 + (k >> 2) * 16 + quad * 4 + rg;
        float v = (k < 4) ? acc0[rg] : acc1[rg];
        if (row < N_NODES) {
          int gg = batch[row];
          if (gg != gp) {
            if (gp >= 0) atomicAdd(&psum[gp * HID + col], run);
            run = 0.f; gp = gg;
          }
          run += fmaxf(v + bv, 0.f);
        }
      }
      if (gp >= 0) atomicAdd(&psum[gp * HID + col], run);
    }
  }
}

__global__ __launch_bounds__(1024) void k_final(const float* __restrict__ psum,
                                                const int* __restrict__ gs, const int* __restrict__ ge,
                                                const float* __restrict__ linW, const float* __restrict__ linb,
                                                float* __restrict__ out) {
  int i = threadIdx.x;              // 64*16 = 1024
  int g = i >> 4, c = i & 15;
  float inv = 1.f / fmaxf((float)(ge[g] - gs[g]), 1.f);
  float s = 0.f;
  #pragma unroll 8
  for (int k = 0; k < HID; ++k) s += psum[g * HID + k] * linW[k * NUM_CLASSES + c];
  out[i] = s * inv + linb[c];
}

// ---------- launch ----------
extern "C" void kernel_launch(void* const* d_in, const int* in_sizes, int n_in,
                              void* d_out, int out_size, void* d_ws, size_t ws_size,
                              hipStream_t stream) {
  const float* x     = (const float*)d_in[0];
  const int*   ei    = (const int*)d_in[1];   // [2,E]: [0..E) src, [E..2E) dst
  const int*   et    = (const int*)d_in[2];
  const int*   batch = (const int*)d_in[3];
  const float* W1    = (const float*)d_in[4];
  const float* root1 = (const float*)d_in[5];
  const float* b1    = (const float*)d_in[6];
  const float* W2    = (const float*)d_in[7];
  const float* root2 = (const float*)d_in[8];
  const float* b2    = (const float*)d_in[9];
  const float* linW  = (const float*)d_in[10];
  const float* linb  = (const float*)d_in[11];
  float* out = (float*)d_out;

  char* ws = (char*)d_ws;
  size_t off = 0;
  auto alloc = [&](size_t bytes) -> char* {
    char* p = ws + off;
    off += (bytes + 255) & ~(size_t)255;
    return p;
  };
  // zero-region: deg | gb | psum (contiguous, one memset)
  int*      deg   = (int*)alloc((size_t)N_NODES * 4);
  int*      gb    = (int*)alloc(2 * NUM_GRAPHS * 4);
  float*    psum  = (float*)alloc((size_t)NUM_GRAPHS * HID * 4);
  size_t zbytes = (((size_t)N_NODES * 4 + 255) & ~(size_t)255) + 512 + (size_t)NUM_GRAPHS * HID * 4;
  int*      gs    = gb;
  int*      ge    = gb + NUM_GRAPHS;
  int*      offs  = (int*)alloc((size_t)(N_NODES + 1) * 4);
  int*      nxt   = (int*)alloc((size_t)N_NODES * 4);
  int*      bsum  = (int*)alloc(512 * 4);
  uint32_t* epack = (uint32_t*)alloc((size_t)N_EDGES * 4);
  uint16_t* Wf1   = (uint16_t*)alloc((size_t)KOUT * KIN * 2);
  uint16_t* Wf2   = (uint16_t*)alloc((size_t)KOUT * KIN * 2);
  uint16_t* xb    = (uint16_t*)alloc((size_t)N_NODES * HID * 2);
  uint16_t* h1b   = (uint16_t*)alloc((size_t)N_NODES * HID * 2);

  hipMemsetAsync(deg, 0, zbytes, stream);

  int nb = (N_NODES + 1023) / 1024;     // 49
  k_prep<<<HIST_B + BND_B + 2 * PW_B + CVT_B, 256, 0, stream>>>(
      ei, et, deg, batch, gs, ge, W1, root1, Wf1, W2, root2, Wf2, x, xb);
  k_scan1<<<nb, 256, 0, stream>>>(deg, offs, bsum);
  k_scan2<<<1, 512, 0, stream>>>(bsum, nb);
  k_scan3<<<(N_NODES + 255) / 256, 256, 0, stream>>>(offs, nxt, bsum);
  k_scatter<<<(N_EDGES + 255) / 256, 256, 0, stream>>>(ei, et, nxt, epack);

  // fused layers: aggregate(h) -> A[32,1152] in LDS -> MFMA with Wcat
  k_fused<0><<<NBLK, 512, 0, stream>>>(xb,  epack, offs, Wf1, b1, h1b, nullptr, nullptr);
  k_fused<1><<<NBLK, 512, 0, stream>>>(h1b, epack, offs, Wf2, b2, nullptr, psum, batch);

  k_final<<<1, 1024, 0, stream>>>(psum, gs, ge, linW, linb, out);
}